// Round 3
// baseline (1305.438 us; speedup 1.0000x reference)
//
#include <hip/hip_runtime.h>

#define F_IN 512
#define HDIM 16
#define F_OUT 40
#define BTGT 64   // targets per bucket
#define REPL 8    // sub-regions per bucket (reservation contention split)

__device__ __forceinline__ int load_src(const void* ei, int is64, int e) {
  return is64 ? (int)((const unsigned int*)ei)[2 * (long long)e] : ((const int*)ei)[e];
}
__device__ __forceinline__ int load_dst(const void* ei, int is64, int e, int E) {
  long long i = (long long)E + e;
  return is64 ? (int)((const unsigned int*)ei)[2 * i] : ((const int*)ei)[i];
}

extern "C" __global__ void k_init(int* __restrict__ hist, int m, int* __restrict__ flag) {
  int i = blockIdx.x * blockDim.x + threadIdx.x;
  if (i < m) hist[i] = 0;
  if (i == 0) *flag = 1;
}

// int64 edge_index => all high halves of first npairs values are zero.
extern "C" __global__ void k_detect(const unsigned int* __restrict__ w, int npairs,
                                    int* __restrict__ flag) {
  int i = blockIdx.x * blockDim.x + threadIdx.x;
  if (i < npairs && w[2 * i + 1] != 0u) atomicAnd(flag, 0);
}

// Fat-block LDS histogram over all M = NBK*REPL sub-buckets.
extern "C" __global__ __launch_bounds__(256) void k_hist(const void* __restrict__ ei, int E,
                                                         int* __restrict__ hist, int M,
                                                         const int* __restrict__ flag) {
  extern __shared__ int lh[];
  int t = threadIdx.x;
  for (int i = t; i < M; i += 256) lh[i] = 0;
  __syncthreads();
  int is64 = *flag;
  int stride = gridDim.x * 256;
  for (int e = blockIdx.x * 256 + t; e < E; e += stride) {
    int c = load_dst(ei, is64, e, E);
    int idx = ((unsigned)c >> 6) * REPL + ((e >> 8) & (REPL - 1));
    atomicAdd(&lh[idx], 1);
  }
  __syncthreads();
  for (int i = t; i < M; i += 256) {
    int v = lh[i];
    if (v) atomicAdd(&hist[i], v);
  }
}

// exclusive scan of M ints in one block; boffs gets M+1 entries, bcur a copy.
extern "C" __global__ __launch_bounds__(1024) void k_scanb(const int* __restrict__ hist,
                                                           int* __restrict__ boffs,
                                                           int* __restrict__ bcur, int M) {
  __shared__ int sh[1024];
  int tid = threadIdx.x;
  int C = (M + 1023) / 1024;
  int base = tid * C;
  int s = 0;
  for (int k = 0; k < C; k++) {
    int idx = base + k;
    if (idx < M) s += hist[idx];
  }
  sh[tid] = s;
  __syncthreads();
  for (int d = 1; d < 1024; d <<= 1) {
    int t2 = (tid >= d) ? sh[tid - d] : 0;
    __syncthreads();
    sh[tid] += t2;
    __syncthreads();
  }
  int run = sh[tid] - s;
  for (int k = 0; k < C; k++) {
    int idx = base + k;
    if (idx < M) {
      int v = hist[idx];
      boffs[idx] = run;
      bcur[idx] = run;
      run += v;
    }
  }
  if (tid == 1023) boffs[M] = run;  // == E
}

// scatter edges into sub-bucket regions as packed words: src | (local_col << 20)
extern "C" __global__ void k_bucket(const void* __restrict__ ei, int E, int* __restrict__ bcur,
                                    unsigned int* __restrict__ bked,
                                    const int* __restrict__ flag) {
  int e = blockIdx.x * 256 + threadIdx.x;
  if (e >= E) return;
  int is64 = *flag;
  int r = load_src(ei, is64, e);
  int c = load_dst(ei, is64, e, E);
  int idx = ((unsigned)c >> 6) * REPL + ((e >> 8) & (REPL - 1));
  int p = atomicAdd(&bcur[idx], 1);
  bked[p] = (unsigned int)r | ((unsigned int)(c & (BTGT - 1)) << 20);
}

// per-bucket local degree count -> dis = rsqrt(deg+1)
extern "C" __global__ __launch_bounds__(256) void k_degb(const unsigned int* __restrict__ bked,
                                                         const int* __restrict__ boffs,
                                                         float* __restrict__ dis, int n) {
  __shared__ int lc[BTGT];
  int b = blockIdx.x, t = threadIdx.x;
  if (t < BTGT) lc[t] = 0;
  __syncthreads();
  int beg = boffs[b * REPL], end = boffs[(b + 1) * REPL];
  for (int p = beg + t; p < end; p += 256) atomicAdd(&lc[bked[p] >> 20], 1);
  __syncthreads();
  if (t < BTGT) {
    int i = b * BTGT + t;
    if (i < n) dis[i] = rsqrtf((float)lc[t] + 1.0f);
  }
}

// hs = dis .* (x @ W1) : 4 threads per row (128 k each), shfl-reduce.
extern "C" __global__ __launch_bounds__(256) void k_mm1s(
    const float* __restrict__ x, const float* __restrict__ W1, const float* __restrict__ dis,
    float* __restrict__ hs, int n) {
  int gt = blockIdx.x * 256 + threadIdx.x;
  int r = gt >> 2, sub = gt & 3;
  if (r >= n) return;
  const float4* xr = (const float4*)(x + (size_t)r * F_IN) + sub * 32;
  float acc[HDIM];
#pragma unroll
  for (int j = 0; j < HDIM; j++) acc[j] = 0.f;
  for (int i = 0; i < 32; i++) {
    float4 xv = xr[i];
    float xk[4] = {xv.x, xv.y, xv.z, xv.w};
    int kbase = sub * 128 + i * 4;
#pragma unroll
    for (int kk = 0; kk < 4; kk++) {
      const float4* wr = (const float4*)(W1 + (size_t)(kbase + kk) * HDIM);
#pragma unroll
      for (int q = 0; q < HDIM / 4; q++) {
        float4 wv = wr[q];
        acc[4 * q + 0] = fmaf(xk[kk], wv.x, acc[4 * q + 0]);
        acc[4 * q + 1] = fmaf(xk[kk], wv.y, acc[4 * q + 1]);
        acc[4 * q + 2] = fmaf(xk[kk], wv.z, acc[4 * q + 2]);
        acc[4 * q + 3] = fmaf(xk[kk], wv.w, acc[4 * q + 3]);
      }
    }
  }
#pragma unroll
  for (int j = 0; j < HDIM; j++) {
    acc[j] += __shfl_xor(acc[j], 1);
    acc[j] += __shfl_xor(acc[j], 2);
  }
  if (sub == 0) {
    float d = dis[r];
    float4* o = (float4*)(hs + (size_t)r * HDIM);
#pragma unroll
    for (int q = 0; q < HDIM / 4; q++)
      o[q] = make_float4(d * acc[4 * q], d * acc[4 * q + 1], d * acc[4 * q + 2],
                         d * acc[4 * q + 3]);
  }
}

// layer-1 aggregate: zs[i] = dis[i] * relu( di*(sum_nb hs[s] + hs[i]) + b1 )
extern "C" __global__ __launch_bounds__(256) void k_agg1(
    const float* __restrict__ hs, const unsigned int* __restrict__ bked,
    const int* __restrict__ boffs, const float* __restrict__ dis,
    const float* __restrict__ b1, float* __restrict__ zs, int n) {
  __shared__ float acc[BTGT * HDIM];
  int b = blockIdx.x, t = threadIdx.x;
  int g = t >> 4, j = t & 15;
  for (int k = t; k < BTGT * HDIM; k += 256) acc[k] = 0.f;
  __syncthreads();
  int beg = boffs[b * REPL], end = boffs[(b + 1) * REPL];
  int total = end - beg;
  int nstripe = total >> 6;
  int pg = beg + (g << 2);
  for (int i = 0; i < nstripe; i++) {
    int p = pg + (i << 6);
    unsigned u0 = bked[p], u1 = bked[p + 1], u2 = bked[p + 2], u3 = bked[p + 3];
    float v0 = hs[(size_t)(u0 & 0xFFFFFu) * HDIM + j];
    float v1 = hs[(size_t)(u1 & 0xFFFFFu) * HDIM + j];
    float v2 = hs[(size_t)(u2 & 0xFFFFFu) * HDIM + j];
    float v3 = hs[(size_t)(u3 & 0xFFFFFu) * HDIM + j];
    atomicAdd(&acc[(u0 >> 20) * HDIM + j], v0);
    atomicAdd(&acc[(u1 >> 20) * HDIM + j], v1);
    atomicAdd(&acc[(u2 >> 20) * HDIM + j], v2);
    atomicAdd(&acc[(u3 >> 20) * HDIM + j], v3);
  }
  int base = beg + (nstripe << 6) + (g << 2);
#pragma unroll
  for (int k = 0; k < 4; k++) {
    int p = base + k;
    if (p < end) {
      unsigned u = bked[p];
      float v = hs[(size_t)(u & 0xFFFFFu) * HDIM + j];
      atomicAdd(&acc[(u >> 20) * HDIM + j], v);
    }
  }
  __syncthreads();
  for (int il = g; il < BTGT; il += 16) {
    int i = b * BTGT + il;
    if (i < n) {
      float di = dis[i];
      float v = di * (acc[il * HDIM + j] + hs[(size_t)i * HDIM + j]) + b1[j];
      v = fmaxf(v, 0.f);
      zs[(size_t)i * HDIM + j] = di * v;
    }
  }
}

// layer-2 aggregate fused with mm2: out[i] = (di*(sum_nb zs[s] + zs[i])) @ W2 + b2
extern "C" __global__ __launch_bounds__(256) void k_agg2f(
    const float* __restrict__ zs, const unsigned int* __restrict__ bked,
    const int* __restrict__ boffs, const float* __restrict__ dis,
    const float* __restrict__ W2, const float* __restrict__ b2, float* __restrict__ out,
    int n) {
  __shared__ float acc[BTGT * HDIM];
  __shared__ float w2s[HDIM * F_OUT];
  __shared__ float b2s[F_OUT];
  int b = blockIdx.x, t = threadIdx.x;
  int g = t >> 4, j = t & 15;
  for (int k = t; k < BTGT * HDIM; k += 256) acc[k] = 0.f;
  for (int k = t; k < HDIM * F_OUT; k += 256) w2s[k] = W2[k];
  if (t < F_OUT) b2s[t] = b2[t];
  __syncthreads();
  int beg = boffs[b * REPL], end = boffs[(b + 1) * REPL];
  int total = end - beg;
  int nstripe = total >> 6;
  int pg = beg + (g << 2);
  for (int i = 0; i < nstripe; i++) {
    int p = pg + (i << 6);
    unsigned u0 = bked[p], u1 = bked[p + 1], u2 = bked[p + 2], u3 = bked[p + 3];
    float v0 = zs[(size_t)(u0 & 0xFFFFFu) * HDIM + j];
    float v1 = zs[(size_t)(u1 & 0xFFFFFu) * HDIM + j];
    float v2 = zs[(size_t)(u2 & 0xFFFFFu) * HDIM + j];
    float v3 = zs[(size_t)(u3 & 0xFFFFFu) * HDIM + j];
    atomicAdd(&acc[(u0 >> 20) * HDIM + j], v0);
    atomicAdd(&acc[(u1 >> 20) * HDIM + j], v1);
    atomicAdd(&acc[(u2 >> 20) * HDIM + j], v2);
    atomicAdd(&acc[(u3 >> 20) * HDIM + j], v3);
  }
  int base = beg + (nstripe << 6) + (g << 2);
#pragma unroll
  for (int k = 0; k < 4; k++) {
    int p = base + k;
    if (p < end) {
      unsigned u = bked[p];
      float v = zs[(size_t)(u & 0xFFFFFu) * HDIM + j];
      atomicAdd(&acc[(u >> 20) * HDIM + j], v);
    }
  }
  __syncthreads();
  for (int il = g; il < BTGT; il += 16) {
    int i = b * BTGT + il;
    if (i < n) {
      float di = dis[i];
      acc[il * HDIM + j] = di * (acc[il * HDIM + j] + zs[(size_t)i * HDIM + j]);
    }
  }
  __syncthreads();
  int il = t >> 2, qo = t & 3;
  int i = b * BTGT + il;
  if (i < n) {
    float tv[HDIM];
#pragma unroll
    for (int k = 0; k < HDIM; k++) tv[k] = acc[il * HDIM + k];
#pragma unroll
    for (int jj = 0; jj < 10; jj++) {
      int col = qo * 10 + jj;
      float s = b2s[col];
#pragma unroll
      for (int k = 0; k < HDIM; k++) s = fmaf(tv[k], w2s[k * F_OUT + col], s);
      out[(size_t)i * F_OUT + col] = s;
    }
  }
}

extern "C" void kernel_launch(void* const* d_in, const int* in_sizes, int n_in,
                              void* d_out, int out_size, void* d_ws, size_t ws_size,
                              hipStream_t stream) {
  const float* x = (const float*)d_in[0];
  const void* ei = d_in[1];
  const float* W1 = (const float*)d_in[2];
  const float* b1 = (const float*)d_in[3];
  const float* W2 = (const float*)d_in[4];
  const float* b2 = (const float*)d_in[5];
  float* out = (float*)d_out;

  const int n = in_sizes[0] / F_IN;  // 100000
  const int E = in_sizes[1] / 2;     // 3200000
  const int NBK = (n + BTGT - 1) / BTGT;  // 1563
  const int M = NBK * REPL;               // 12504

  char* w = (char*)d_ws;
  auto alloc = [&](size_t bytes) {
    char* p = w;
    w += (bytes + 255) & ~(size_t)255;
    return p;
  };
  int* flag = (int*)alloc(4);
  int* hist = (int*)alloc((size_t)M * 4);
  int* boffs = (int*)alloc((size_t)(M + 1) * 4);
  int* bcur = (int*)alloc((size_t)M * 4);
  float* dis = (float*)alloc((size_t)n * 4);
  unsigned int* bked = (unsigned int*)alloc((size_t)E * 4);
  float* hs = (float*)alloc((size_t)n * HDIM * 4);
  float* zs = (float*)alloc((size_t)n * HDIM * 4);

  dim3 B(256);
  hipLaunchKernelGGL(k_init, dim3((M + 255) / 256), B, 0, stream, hist, M, flag);
  int npairs = 4096;
  if (npairs > E) npairs = E;
  hipLaunchKernelGGL(k_detect, dim3((npairs + 255) / 256), B, 0, stream,
                     (const unsigned int*)ei, npairs, flag);
  hipLaunchKernelGGL(k_hist, dim3(128), B, (size_t)M * 4, stream, ei, E, hist, M, flag);
  hipLaunchKernelGGL(k_scanb, dim3(1), dim3(1024), 0, stream, hist, boffs, bcur, M);
  hipLaunchKernelGGL(k_bucket, dim3((E + 255) / 256), B, 0, stream, ei, E, bcur, bked, flag);
  hipLaunchKernelGGL(k_degb, dim3(NBK), B, 0, stream, bked, boffs, dis, n);
  hipLaunchKernelGGL(k_mm1s, dim3((n * 4 + 255) / 256), B, 0, stream, x, W1, dis, hs, n);
  hipLaunchKernelGGL(k_agg1, dim3(NBK), B, 0, stream, hs, bked, boffs, dis, b1, zs, n);
  hipLaunchKernelGGL(k_agg2f, dim3(NBK), B, 0, stream, zs, bked, boffs, dis, W2, b2, out, n);
}

// Round 5
// 945.761 us; speedup vs baseline: 1.3803x; 1.3803x over previous
//
#include <hip/hip_runtime.h>

#define F_IN 512
#define HDIM 16
#define F_OUT 40
#define BTGT 64   // targets per bucket
#define REPL 8    // sub-regions per bucket == XCD partitions
#define NCH 512   // blocks for edge-chunked kernels (hist/bucket)

__device__ __forceinline__ int load_src(const void* ei, int is64, int e) {
  return is64 ? (int)((const unsigned int*)ei)[2 * (long long)e] : ((const int*)ei)[e];
}
__device__ __forceinline__ int load_dst(const void* ei, int is64, int e, int E) {
  long long i = (long long)E + e;
  return is64 ? (int)((const unsigned int*)ei)[2 * i] : ((const int*)ei)[i];
}

extern "C" __global__ void k_init(int* __restrict__ hist, int m, int* __restrict__ flag) {
  int i = blockIdx.x * blockDim.x + threadIdx.x;
  if (i < m) hist[i] = 0;
  if (i == 0) *flag = 1;
}

// int64 edge_index => all high halves of first npairs values are zero.
extern "C" __global__ void k_detect(const unsigned int* __restrict__ w, int npairs,
                                    int* __restrict__ flag) {
  int i = blockIdx.x * blockDim.x + threadIdx.x;
  if (i < npairs && w[2 * i + 1] != 0u) atomicAnd(flag, 0);
}

// Per-block LDS histogram of its own replica slice (NBK counters), replica = blockIdx&7.
// Edge->block mapping MUST match k_bucket (contiguous chunks of size echunk).
extern "C" __global__ __launch_bounds__(256) void k_hist(const void* __restrict__ ei, int E,
                                                         int echunk, int* __restrict__ hist,
                                                         int NBK,
                                                         const int* __restrict__ flag) {
  extern __shared__ int lh[];
  int g = blockIdx.x, t = threadIdx.x;
  for (int i = t; i < NBK; i += 256) lh[i] = 0;
  __syncthreads();
  int is64 = *flag;
  int e0 = g * echunk;
  int e1 = e0 + echunk;
  if (e1 > E) e1 = E;
  for (int e = e0 + t; e < e1; e += 256) {
    int c = load_dst(ei, is64, e, E);
    atomicAdd(&lh[(unsigned)c >> 6], 1);
  }
  __syncthreads();
  int repl = g & (REPL - 1);
  for (int i = t; i < NBK; i += 256) {
    int v = lh[i];
    if (v) atomicAdd(&hist[i * REPL + repl], v);
  }
}

// exclusive scan of M ints in one block; boffs gets M+1 entries, bcur a copy.
extern "C" __global__ __launch_bounds__(1024) void k_scanb(const int* __restrict__ hist,
                                                           int* __restrict__ boffs,
                                                           int* __restrict__ bcur, int M) {
  __shared__ int sh[1024];
  int tid = threadIdx.x;
  int C = (M + 1023) / 1024;
  int base = tid * C;
  int s = 0;
  for (int k = 0; k < C; k++) {
    int idx = base + k;
    if (idx < M) s += hist[idx];
  }
  sh[tid] = s;
  __syncthreads();
  for (int d = 1; d < 1024; d <<= 1) {
    int t2 = (tid >= d) ? sh[tid - d] : 0;
    __syncthreads();
    sh[tid] += t2;
    __syncthreads();
  }
  int run = sh[tid] - s;
  for (int k = 0; k < C; k++) {
    int idx = base + k;
    if (idx < M) {
      int v = hist[idx];
      boffs[idx] = run;
      bcur[idx] = run;
      run += v;
    }
  }
  if (tid == 1023) boffs[M] = run;  // == E
}

// scatter edges as packed words src | (local_col<<20) into sub-region (bucket, blockIdx&7).
// Same chunking as k_hist so reservations match histogram counts.
extern "C" __global__ __launch_bounds__(256) void k_bucket(const void* __restrict__ ei, int E,
                                                           int echunk, int* __restrict__ bcur,
                                                           unsigned int* __restrict__ bked,
                                                           const int* __restrict__ flag) {
  int g = blockIdx.x, t = threadIdx.x;
  int is64 = *flag;
  int repl = g & (REPL - 1);
  int e0 = g * echunk;
  int e1 = e0 + echunk;
  if (e1 > E) e1 = E;
  for (int e = e0 + t; e < e1; e += 256) {
    int r = load_src(ei, is64, e);
    int c = load_dst(ei, is64, e, E);
    int idx = ((unsigned)c >> 6) * REPL + repl;
    int p = atomicAdd(&bcur[idx], 1);
    bked[p] = (unsigned int)r | ((unsigned int)(c & (BTGT - 1)) << 20);
  }
}

// per-bucket local degree count -> dis = rsqrt(deg+1)
extern "C" __global__ __launch_bounds__(256) void k_degb(const unsigned int* __restrict__ bked,
                                                         const int* __restrict__ boffs,
                                                         float* __restrict__ dis, int n) {
  __shared__ int lc[BTGT];
  int b = blockIdx.x, t = threadIdx.x;
  if (t < BTGT) lc[t] = 0;
  __syncthreads();
  int beg = boffs[b * REPL], end = boffs[(b + 1) * REPL];
  for (int p = beg + t; p < end; p += 256) atomicAdd(&lc[bked[p] >> 20], 1);
  __syncthreads();
  if (t < BTGT) {
    int i = b * BTGT + t;
    if (i < n) dis[i] = rsqrtf((float)lc[t] + 1.0f);
  }
}

// hs = dis .* (x @ W1). Block = 256 rows, LDS-staged x tile (coalesced global loads,
// XOR-swizzled float4 columns), W1 broadcast from LDS. One row per thread.
extern "C" __global__ __launch_bounds__(256) void k_mm1s(
    const float* __restrict__ x, const float* __restrict__ W1, const float* __restrict__ dis,
    float* __restrict__ hs, int n) {
  __shared__ float xs[256 * 32];      // 32 KB tile: rows x 32 k, float4-swizzled
  __shared__ float w1s[F_IN * HDIM];  // 32 KB
  int t = threadIdx.x;
  int row0 = blockIdx.x * 256;
  {
    const float4* wg = (const float4*)W1;
    float4* wl = (float4*)w1s;
    for (int i = t; i < F_IN * HDIM / 4; i += 256) wl[i] = wg[i];
  }
  int r = row0 + t;
  bool active = (r < n);
  bool fullblk = (row0 + 255 < n);
  float acc[HDIM];
#pragma unroll
  for (int j = 0; j < HDIM; j++) acc[j] = 0.f;

  float4* xs4 = (float4*)xs;
  for (int kc = 0; kc < F_IN / 32; kc++) {
    __syncthreads();
    if (fullblk) {
#pragma unroll
      for (int it = 0; it < 8; it++) {
        int f = it * 256 + t;
        int r2 = f >> 3, fi = f & 7;
        float4 v = ((const float4*)(x + (size_t)(row0 + r2) * F_IN + kc * 32))[fi];
        xs4[r2 * 8 + (fi ^ (r2 & 7))] = v;
      }
    } else {
      for (int it = 0; it < 8; it++) {
        int f = it * 256 + t;
        int r2 = f >> 3, fi = f & 7;
        float4 v = make_float4(0.f, 0.f, 0.f, 0.f);
        if (row0 + r2 < n)
          v = ((const float4*)(x + (size_t)(row0 + r2) * F_IN + kc * 32))[fi];
        xs4[r2 * 8 + (fi ^ (r2 & 7))] = v;
      }
    }
    __syncthreads();
    if (active) {
#pragma unroll
      for (int i = 0; i < 8; i++) {
        int ii = i ^ (t & 7);               // slot holding logical column chunk i
        float4 xv = xs4[t * 8 + ii];        // == x[row t][cols kc*32 + i*4 ..]
        float xk[4] = {xv.x, xv.y, xv.z, xv.w};
        int kb = kc * 32 + i * 4;           // FIX: logical column index, not slot
#pragma unroll
        for (int kk = 0; kk < 4; kk++) {
          const float4* wr = (const float4*)(w1s + (size_t)(kb + kk) * HDIM);
#pragma unroll
          for (int q = 0; q < HDIM / 4; q++) {
            float4 wv = wr[q];
            acc[4 * q + 0] = fmaf(xk[kk], wv.x, acc[4 * q + 0]);
            acc[4 * q + 1] = fmaf(xk[kk], wv.y, acc[4 * q + 1]);
            acc[4 * q + 2] = fmaf(xk[kk], wv.z, acc[4 * q + 2]);
            acc[4 * q + 3] = fmaf(xk[kk], wv.w, acc[4 * q + 3]);
          }
        }
      }
    }
  }
  if (active) {
    float d = dis[r];
    float4* o = (float4*)(hs + (size_t)r * HDIM);
#pragma unroll
    for (int q = 0; q < HDIM / 4; q++)
      o[q] = make_float4(d * acc[4 * q], d * acc[4 * q + 1], d * acc[4 * q + 2],
                         d * acc[4 * q + 3]);
  }
}

// layer-1 aggregate: zs[i] = dis[i] * relu( di*(sum_nb hs[s] + hs[i]) + b1 )
// 16-lane groups, 8 edges in flight per group.
extern "C" __global__ __launch_bounds__(256) void k_agg1(
    const float* __restrict__ hs, const unsigned int* __restrict__ bked,
    const int* __restrict__ boffs, const float* __restrict__ dis,
    const float* __restrict__ b1, float* __restrict__ zs, int n) {
  __shared__ float acc[BTGT * HDIM];
  int b = blockIdx.x, t = threadIdx.x;
  int g = t >> 4, j = t & 15;
  for (int k = t; k < BTGT * HDIM; k += 256) acc[k] = 0.f;
  __syncthreads();
  int beg = boffs[b * REPL], end = boffs[(b + 1) * REPL];
  int total = end - beg;
  int nfull = total >> 7;  // stripes of 128 = 16 groups x 8
  int pbase = beg + (g << 3);
  for (int s2 = 0; s2 < nfull; s2++) {
    int p = pbase + (s2 << 7);
    unsigned u[8];
    float v[8];
#pragma unroll
    for (int k = 0; k < 8; k++) u[k] = bked[p + k];
#pragma unroll
    for (int k = 0; k < 8; k++) v[k] = hs[(size_t)(u[k] & 0xFFFFFu) * HDIM + j];
#pragma unroll
    for (int k = 0; k < 8; k++) atomicAdd(&acc[(u[k] >> 20) * HDIM + j], v[k]);
  }
  for (int p = beg + (nfull << 7) + g; p < end; p += 16) {
    unsigned u = bked[p];
    float v = hs[(size_t)(u & 0xFFFFFu) * HDIM + j];
    atomicAdd(&acc[(u >> 20) * HDIM + j], v);
  }
  __syncthreads();
  for (int il = g; il < BTGT; il += 16) {
    int i = b * BTGT + il;
    if (i < n) {
      float di = dis[i];
      float v = di * (acc[il * HDIM + j] + hs[(size_t)i * HDIM + j]) + b1[j];
      v = fmaxf(v, 0.f);
      zs[(size_t)i * HDIM + j] = di * v;
    }
  }
}

// layer-2 aggregate fused with mm2: out = (di*(sum_nb zs[s] + zs[i])) @ W2 + b2
extern "C" __global__ __launch_bounds__(256) void k_agg2f(
    const float* __restrict__ zs, const unsigned int* __restrict__ bked,
    const int* __restrict__ boffs, const float* __restrict__ dis,
    const float* __restrict__ W2, const float* __restrict__ b2, float* __restrict__ out,
    int n) {
  __shared__ float acc[BTGT * HDIM];
  __shared__ float w2s[HDIM * F_OUT];
  __shared__ float b2s[F_OUT];
  int b = blockIdx.x, t = threadIdx.x;
  int g = t >> 4, j = t & 15;
  for (int k = t; k < BTGT * HDIM; k += 256) acc[k] = 0.f;
  for (int k = t; k < HDIM * F_OUT; k += 256) w2s[k] = W2[k];
  if (t < F_OUT) b2s[t] = b2[t];
  __syncthreads();
  int beg = boffs[b * REPL], end = boffs[(b + 1) * REPL];
  int total = end - beg;
  int nfull = total >> 7;
  int pbase = beg + (g << 3);
  for (int s2 = 0; s2 < nfull; s2++) {
    int p = pbase + (s2 << 7);
    unsigned u[8];
    float v[8];
#pragma unroll
    for (int k = 0; k < 8; k++) u[k] = bked[p + k];
#pragma unroll
    for (int k = 0; k < 8; k++) v[k] = zs[(size_t)(u[k] & 0xFFFFFu) * HDIM + j];
#pragma unroll
    for (int k = 0; k < 8; k++) atomicAdd(&acc[(u[k] >> 20) * HDIM + j], v[k]);
  }
  for (int p = beg + (nfull << 7) + g; p < end; p += 16) {
    unsigned u = bked[p];
    float v = zs[(size_t)(u & 0xFFFFFu) * HDIM + j];
    atomicAdd(&acc[(u >> 20) * HDIM + j], v);
  }
  __syncthreads();
  for (int il = g; il < BTGT; il += 16) {
    int i = b * BTGT + il;
    if (i < n) {
      float di = dis[i];
      acc[il * HDIM + j] = di * (acc[il * HDIM + j] + zs[(size_t)i * HDIM + j]);
    }
  }
  __syncthreads();
  int il = t >> 2, qo = t & 3;
  int i = b * BTGT + il;
  if (i < n) {
    float tv[HDIM];
#pragma unroll
    for (int k = 0; k < HDIM; k++) tv[k] = acc[il * HDIM + k];
#pragma unroll
    for (int jj = 0; jj < 10; jj++) {
      int col = qo * 10 + jj;
      float s = b2s[col];
#pragma unroll
      for (int k = 0; k < HDIM; k++) s = fmaf(tv[k], w2s[k * F_OUT + col], s);
      out[(size_t)i * F_OUT + col] = s;
    }
  }
}

extern "C" void kernel_launch(void* const* d_in, const int* in_sizes, int n_in,
                              void* d_out, int out_size, void* d_ws, size_t ws_size,
                              hipStream_t stream) {
  const float* x = (const float*)d_in[0];
  const void* ei = d_in[1];
  const float* W1 = (const float*)d_in[2];
  const float* b1 = (const float*)d_in[3];
  const float* W2 = (const float*)d_in[4];
  const float* b2 = (const float*)d_in[5];
  float* out = (float*)d_out;

  const int n = in_sizes[0] / F_IN;  // 100000
  const int E = in_sizes[1] / 2;     // 3200000
  const int NBK = (n + BTGT - 1) / BTGT;  // 1563
  const int M = NBK * REPL;               // 12504
  const int echunk = (E + NCH - 1) / NCH;

  char* w = (char*)d_ws;
  auto alloc = [&](size_t bytes) {
    char* p = w;
    w += (bytes + 255) & ~(size_t)255;
    return p;
  };
  int* flag = (int*)alloc(4);
  int* hist = (int*)alloc((size_t)M * 4);
  int* boffs = (int*)alloc((size_t)(M + 1) * 4);
  int* bcur = (int*)alloc((size_t)M * 4);
  float* dis = (float*)alloc((size_t)n * 4);
  unsigned int* bked = (unsigned int*)alloc((size_t)E * 4);
  float* hs = (float*)alloc((size_t)n * HDIM * 4);
  float* zs = (float*)alloc((size_t)n * HDIM * 4);

  dim3 B(256);
  hipLaunchKernelGGL(k_init, dim3((M + 255) / 256), B, 0, stream, hist, M, flag);
  int npairs = 4096;
  if (npairs > E) npairs = E;
  hipLaunchKernelGGL(k_detect, dim3((npairs + 255) / 256), B, 0, stream,
                     (const unsigned int*)ei, npairs, flag);
  hipLaunchKernelGGL(k_hist, dim3(NCH), B, (size_t)NBK * 4, stream, ei, E, echunk, hist, NBK,
                     flag);
  hipLaunchKernelGGL(k_scanb, dim3(1), dim3(1024), 0, stream, hist, boffs, bcur, M);
  hipLaunchKernelGGL(k_bucket, dim3(NCH), B, 0, stream, ei, E, echunk, bcur, bked, flag);
  hipLaunchKernelGGL(k_degb, dim3(NBK), B, 0, stream, bked, boffs, dis, n);
  hipLaunchKernelGGL(k_mm1s, dim3((n + 255) / 256), B, 0, stream, x, W1, dis, hs, n);
  hipLaunchKernelGGL(k_agg1, dim3(NBK), B, 0, stream, hs, bked, boffs, dis, b1, zs, n);
  hipLaunchKernelGGL(k_agg2f, dim3(NBK), B, 0, stream, zs, bked, boffs, dis, W2, b2, out, n);
}